// Round 6
// baseline (39.382 us; speedup 1.0000x reference)
//
#include <hip/hip_runtime.h>
#include <hip/hip_bf16.h>
#include <math.h>

// Problem constants: B=4, Q=100, T=20, H=W=128 (HW=16384), C=80
#define B_ 4
#define Q_ 100
#define T_ 20
#define C_ 80
#define HW_ 16384

#define S_ 16                    // segments over HW
#define QG_ 4                    // queries per group/block
#define GPB_ (Q_ / QG_)          // 25 groups per batch
#define GROUPS_ (B_ * GPB_)      // 100
#define SEG4_ (HW_ / S_ / 4)     // 256 float4 per segment
#define TW_ 5                    // t's per wave (4 waves * 5 = T)
#define SUBS_ 4                  // partial-reduce width (lanes 0..3)
#define QREC_ 41                 // per-q: 20 L + 20 I + 1 osum
#define REC_ (QG_ * QREC_ * SUBS_)      // 656 floats per (group,seg)
#define GWS_OFF ((size_t)GROUPS_ * S_ * REC_)  // gsum area: [B][S][T][SUBS_]

// 4-stage reduce: lanes 0..3 end with disjoint 16-lane partial sums.
__device__ __forceinline__ float wave_reduce4(float v) {
    v += __shfl_down(v, 32);
    v += __shfl_down(v, 16);
    v += __shfl_down(v, 8);
    v += __shfl_down(v, 4);
    return v;
}

template <bool WITH_G>
__device__ __forceinline__ void partial_body(const float4* __restrict__ o4,
                                             const float4* __restrict__ g4,
                                             float* __restrict__ rec,
                                             float* __restrict__ grec,
                                             int lane, int wave) {
    const int t0 = wave * TW_;

    float accL[QG_][TW_];
    float accI[QG_][TW_];
    float osum[QG_];
    float gsum[TW_];
#pragma unroll
    for (int qi = 0; qi < QG_; ++qi) {
        osum[qi] = 0.f;
#pragma unroll
        for (int tj = 0; tj < TW_; ++tj) { accL[qi][tj] = 0.f; accI[qi][tj] = 0.f; }
    }
#pragma unroll
    for (int tj = 0; tj < TW_; ++tj) gsum[tj] = 0.f;

    for (int i = lane; i < SEG4_; i += 64) {
        float4 o[QG_];
#pragma unroll
        for (int qi = 0; qi < QG_; ++qi) {
            o[qi] = o4[(size_t)qi * (HW_ / 4) + i];
            osum[qi] += (o[qi].x + o[qi].y) + (o[qi].z + o[qi].w);
        }
#pragma unroll
        for (int tj = 0; tj < TW_; ++tj) {
            const float4 g = g4[(size_t)(t0 + tj) * (HW_ / 4) + i];
            if (WITH_G) gsum[tj] += (g.x + g.y) + (g.z + g.w);
#pragma unroll
            for (int qi = 0; qi < QG_; ++qi) {
                accL[qi][tj] += (fabsf(o[qi].x - g.x) + fabsf(o[qi].y - g.y)) +
                                (fabsf(o[qi].z - g.z) + fabsf(o[qi].w - g.w));
                accI[qi][tj] = fmaf(o[qi].x, g.x, accI[qi][tj]);
                accI[qi][tj] = fmaf(o[qi].y, g.y, accI[qi][tj]);
                accI[qi][tj] = fmaf(o[qi].z, g.z, accI[qi][tj]);
                accI[qi][tj] = fmaf(o[qi].w, g.w, accI[qi][tj]);
            }
        }
    }

#pragma unroll
    for (int qi = 0; qi < QG_; ++qi) {
#pragma unroll
        for (int tj = 0; tj < TW_; ++tj) {
            const float vL = wave_reduce4(accL[qi][tj]);
            const float vI = wave_reduce4(accI[qi][tj]);
            if (lane < SUBS_) {
                rec[(qi * QREC_ + (t0 + tj)) * SUBS_ + lane]      = vL;
                rec[(qi * QREC_ + 20 + (t0 + tj)) * SUBS_ + lane] = vI;
            }
        }
        const float vo = wave_reduce4(osum[qi]);
        if (wave == 0 && lane < SUBS_) rec[(qi * QREC_ + 40) * SUBS_ + lane] = vo;
    }
    if (WITH_G) {
#pragma unroll
        for (int tj = 0; tj < TW_; ++tj) {
            const float vg = wave_reduce4(gsum[tj]);
            if (lane < SUBS_) grec[(t0 + tj) * SUBS_ + lane] = vg;
        }
    }
}

// Kernel 1: partial sums per (4-query group, segment), XCD-batch-partitioned.
// blockIdx remap: XCDs {2b,2b+1} serve batch b so its targets stay L2-resident.
__global__ __launch_bounds__(256) void partial_kernel(const float* __restrict__ outm,
                                                      const float* __restrict__ tgtm,
                                                      float* __restrict__ ws) {
    const int r = blockIdx.x & 7;
    const int m = blockIdx.x >> 3;
    const int b = r >> 1;                  // batch = XCD-pair
    const int l = m * 2 + (r & 1);         // [0, 400) local index within batch
    const int grp_local = l >> 4;          // [0, 25)
    const int seg = l & (S_ - 1);          // [0, 16)
    const int qbase = grp_local * QG_;
    const int grp = b * GPB_ + grp_local;

    const int lane = threadIdx.x & 63;
    const int wave = threadIdx.x >> 6;

    const float4* o4 = (const float4*)(outm + ((size_t)b * Q_ + qbase) * HW_) + seg * SEG4_;
    const float4* g4 = (const float4*)(tgtm + (size_t)b * T_ * HW_) + seg * SEG4_;
    float* rec  = ws + (size_t)(grp * S_ + seg) * REC_;
    float* grec = ws + GWS_OFF + (size_t)(b * S_ + seg) * T_ * SUBS_;

    if (grp_local == 0) partial_body<true>(o4, g4, rec, grec, lane, wave);
    else                partial_body<false>(o4, g4, rec, grec, lane, wave);
}

// Kernel 2: reduce segments/sub-partials + epilogue (softmax class cost + dice).
__global__ __launch_bounds__(64) void finalize_kernel(const float* __restrict__ probs,
                                                      const int*   __restrict__ labels,
                                                      const float* __restrict__ ws,
                                                      float* __restrict__ out) {
    const int bq = blockIdx.x;
    const int b = bq / Q_;
    const int q = bq % Q_;
    const int grp = b * GPB_ + q / QG_;
    const int qi  = q % QG_;

    __shared__ float s_logit[C_];
    for (int c = threadIdx.x; c < C_; c += 64)
        s_logit[c] = probs[(size_t)bq * C_ + c];
    __syncthreads();

    const int t = threadIdx.x;
    if (t < T_) {
        float L = 0.f, I = 0.f, os = 0.f, ts = 0.f;
#pragma unroll
        for (int s = 0; s < S_; ++s) {
            const float4* r4 = (const float4*)(ws + (size_t)(grp * S_ + s) * REC_);
            const float4* d4 = (const float4*)(ws + GWS_OFF + (size_t)(b * S_ + s) * T_ * SUBS_);
            const float4 a = r4[qi * QREC_ + t];
            const float4 v = r4[qi * QREC_ + 20 + t];
            const float4 c = r4[qi * QREC_ + 40];
            const float4 d = d4[t];
            L  += (a.x + a.y) + (a.z + a.w);
            I  += (v.x + v.y) + (v.z + v.w);
            os += (c.x + c.y) + (c.z + c.w);
            ts += (d.x + d.y) + (d.z + d.w);
        }
        float mx = -INFINITY;
#pragma unroll
        for (int c = 0; c < C_; ++c) mx = fmaxf(mx, s_logit[c]);
        float sum = 0.f;
#pragma unroll
        for (int c = 0; c < C_; ++c) sum += __expf(s_logit[c] - mx);
        const int lab = labels[b * T_ + t];
        const float p = __expf(s_logit[lab] - mx) / sum;

        const float denom = os + ts;
        const float dice = 1.f - (2.f * I + 1.f) / (denom + 1.f);

        out[(size_t)bq * T_ + t] = L - p + dice;
    }
}

extern "C" void kernel_launch(void* const* d_in, const int* in_sizes, int n_in,
                              void* d_out, int out_size, void* d_ws, size_t ws_size,
                              hipStream_t stream) {
    const float* out_probs     = (const float*)d_in[0]; // [B,Q,C]
    const float* out_masks     = (const float*)d_in[1]; // [B,Q,H,W]
    const float* target_masks  = (const float*)d_in[2]; // [B,T,H,W]
    const int*   target_labels = (const int*)d_in[3];   // [B,T]
    float* out = (float*)d_out;                         // [B,Q,T]

    float* partials = (float*)d_ws;                     // ~4.2 MB + 20 KB gsum

    partial_kernel<<<GROUPS_ * S_, 256, 0, stream>>>(out_masks, target_masks, partials);
    finalize_kernel<<<B_ * Q_, 64, 0, stream>>>(out_probs, target_labels, partials, out);
}

// Round 7
// 37.288 us; speedup vs baseline: 1.0562x; 1.0562x over previous
//
#include <hip/hip_runtime.h>
#include <hip/hip_bf16.h>
#include <math.h>

// Problem constants: B=4, Q=100, T=20, H=W=128 (HW=16384), C=80
#define B_ 4
#define Q_ 100
#define T_ 20
#define C_ 80
#define HW_ 16384

#define S_ 16                    // segments over HW
#define QG_ 4                    // queries per group/block
#define GPB_ (Q_ / QG_)          // 25 groups per batch
#define GROUPS_ (B_ * GPB_)      // 100
#define SEG4_ (HW_ / S_ / 4)     // 256 float4 per segment
#define NITER_ (SEG4_ / 64)      // 4 iterations per wave
#define TW_ 5                    // t's per wave (4 waves * 5 = T)
#define SUBS_ 4                  // partial-reduce width (lanes 0..3)
#define QREC_ 41                 // per-q: 20 L + 20 I + 1 osum
#define REC_ (QG_ * QREC_ * SUBS_)      // 656 floats per (group,seg)
#define GWS_OFF ((size_t)GROUPS_ * S_ * REC_)  // gsum area: [B][S][T][SUBS_]

typedef float f32x4 __attribute__((ext_vector_type(4)));

__device__ __forceinline__ f32x4 ldnt(const f32x4* p) {
    return __builtin_nontemporal_load(p);   // stream: don't cache in L2
}

// 4-stage reduce: lanes 0..3 end with disjoint 16-lane partial sums.
__device__ __forceinline__ float wave_reduce4(float v) {
    v += __shfl_down(v, 32);
    v += __shfl_down(v, 16);
    v += __shfl_down(v, 8);
    v += __shfl_down(v, 4);
    return v;
}

template <bool WITH_G>
__device__ __forceinline__ void partial_body(const f32x4* __restrict__ o4,
                                             const f32x4* __restrict__ g4,
                                             float* __restrict__ rec,
                                             float* __restrict__ grec,
                                             int lane, int wave) {
    const int t0 = wave * TW_;

    float accL[QG_][TW_];
    float accI[QG_][TW_];
    float osum[QG_];
    float gsum[TW_];
#pragma unroll
    for (int qi = 0; qi < QG_; ++qi) {
        osum[qi] = 0.f;
#pragma unroll
        for (int tj = 0; tj < TW_; ++tj) { accL[qi][tj] = 0.f; accI[qi][tj] = 0.f; }
    }
#pragma unroll
    for (int tj = 0; tj < TW_; ++tj) gsum[tj] = 0.f;

    const f32x4* op = o4 + lane;
    const f32x4* gp = g4 + (size_t)t0 * (HW_ / 4) + lane;

    f32x4 oc[QG_], gc[TW_], on[QG_], gn[TW_];
    // Preload iteration 0 (one contiguous batch of 9 loads).
#pragma unroll
    for (int qi = 0; qi < QG_; ++qi) oc[qi] = ldnt(op + (size_t)qi * (HW_ / 4));
#pragma unroll
    for (int tj = 0; tj < TW_; ++tj) gc[tj] = gp[(size_t)tj * (HW_ / 4)];

#pragma unroll
    for (int it = 0; it < NITER_; ++it) {
        // Issue next iteration's 9 loads before computing the current one.
        if (it + 1 < NITER_) {
            const int ofs = (it + 1) * 64;
#pragma unroll
            for (int qi = 0; qi < QG_; ++qi) on[qi] = ldnt(op + (size_t)qi * (HW_ / 4) + ofs);
#pragma unroll
            for (int tj = 0; tj < TW_; ++tj) gn[tj] = gp[(size_t)tj * (HW_ / 4) + ofs];
        }
        // Compute with current registers (~250 VALU ops hides the next batch).
#pragma unroll
        for (int qi = 0; qi < QG_; ++qi)
            osum[qi] += (oc[qi].x + oc[qi].y) + (oc[qi].z + oc[qi].w);
#pragma unroll
        for (int tj = 0; tj < TW_; ++tj) {
            const f32x4 g = gc[tj];
            if (WITH_G) gsum[tj] += (g.x + g.y) + (g.z + g.w);
#pragma unroll
            for (int qi = 0; qi < QG_; ++qi) {
                const f32x4 o = oc[qi];
                accL[qi][tj] += (fabsf(o.x - g.x) + fabsf(o.y - g.y)) +
                                (fabsf(o.z - g.z) + fabsf(o.w - g.w));
                accI[qi][tj] = fmaf(o.x, g.x, accI[qi][tj]);
                accI[qi][tj] = fmaf(o.y, g.y, accI[qi][tj]);
                accI[qi][tj] = fmaf(o.z, g.z, accI[qi][tj]);
                accI[qi][tj] = fmaf(o.w, g.w, accI[qi][tj]);
            }
        }
        if (it + 1 < NITER_) {
#pragma unroll
            for (int qi = 0; qi < QG_; ++qi) oc[qi] = on[qi];
#pragma unroll
            for (int tj = 0; tj < TW_; ++tj) gc[tj] = gn[tj];
        }
    }

#pragma unroll
    for (int qi = 0; qi < QG_; ++qi) {
#pragma unroll
        for (int tj = 0; tj < TW_; ++tj) {
            const float vL = wave_reduce4(accL[qi][tj]);
            const float vI = wave_reduce4(accI[qi][tj]);
            if (lane < SUBS_) {
                rec[(qi * QREC_ + (t0 + tj)) * SUBS_ + lane]      = vL;
                rec[(qi * QREC_ + 20 + (t0 + tj)) * SUBS_ + lane] = vI;
            }
        }
        const float vo = wave_reduce4(osum[qi]);
        if (wave == 0 && lane < SUBS_) rec[(qi * QREC_ + 40) * SUBS_ + lane] = vo;
    }
    if (WITH_G) {
#pragma unroll
        for (int tj = 0; tj < TW_; ++tj) {
            const float vg = wave_reduce4(gsum[tj]);
            if (lane < SUBS_) grec[(t0 + tj) * SUBS_ + lane] = vg;
        }
    }
}

// Kernel 1: partial sums per (4-query group, segment), XCD-batch-partitioned.
__global__ __launch_bounds__(256) void partial_kernel(const float* __restrict__ outm,
                                                      const float* __restrict__ tgtm,
                                                      float* __restrict__ ws) {
    const int r = blockIdx.x & 7;
    const int m = blockIdx.x >> 3;
    const int b = r >> 1;                  // batch = XCD-pair
    const int l = m * 2 + (r & 1);         // [0, 400) local index within batch
    const int grp_local = l >> 4;          // [0, 25)
    const int seg = l & (S_ - 1);          // [0, 16)
    const int qbase = grp_local * QG_;
    const int grp = b * GPB_ + grp_local;

    const int lane = threadIdx.x & 63;
    const int wave = threadIdx.x >> 6;

    const f32x4* o4 = (const f32x4*)(outm + ((size_t)b * Q_ + qbase) * HW_) + seg * SEG4_;
    const f32x4* g4 = (const f32x4*)(tgtm + (size_t)b * T_ * HW_) + seg * SEG4_;
    float* rec  = ws + (size_t)(grp * S_ + seg) * REC_;
    float* grec = ws + GWS_OFF + (size_t)(b * S_ + seg) * T_ * SUBS_;

    if (grp_local == 0) partial_body<true>(o4, g4, rec, grec, lane, wave);
    else                partial_body<false>(o4, g4, rec, grec, lane, wave);
}

// Kernel 2: reduce segments/sub-partials + epilogue (softmax class cost + dice).
__global__ __launch_bounds__(64) void finalize_kernel(const float* __restrict__ probs,
                                                      const int*   __restrict__ labels,
                                                      const float* __restrict__ ws,
                                                      float* __restrict__ out) {
    const int bq = blockIdx.x;
    const int b = bq / Q_;
    const int q = bq % Q_;
    const int grp = b * GPB_ + q / QG_;
    const int qi  = q % QG_;

    __shared__ float s_logit[C_];
    for (int c = threadIdx.x; c < C_; c += 64)
        s_logit[c] = probs[(size_t)bq * C_ + c];
    __syncthreads();

    const int t = threadIdx.x;
    if (t < T_) {
        float L = 0.f, I = 0.f, os = 0.f, ts = 0.f;
#pragma unroll
        for (int s = 0; s < S_; ++s) {
            const float4* r4 = (const float4*)(ws + (size_t)(grp * S_ + s) * REC_);
            const float4* d4 = (const float4*)(ws + GWS_OFF + (size_t)(b * S_ + s) * T_ * SUBS_);
            const float4 a = r4[qi * QREC_ + t];
            const float4 v = r4[qi * QREC_ + 20 + t];
            const float4 c = r4[qi * QREC_ + 40];
            const float4 d = d4[t];
            L  += (a.x + a.y) + (a.z + a.w);
            I  += (v.x + v.y) + (v.z + v.w);
            os += (c.x + c.y) + (c.z + c.w);
            ts += (d.x + d.y) + (d.z + d.w);
        }
        float mx = -INFINITY;
#pragma unroll
        for (int c = 0; c < C_; ++c) mx = fmaxf(mx, s_logit[c]);
        float sum = 0.f;
#pragma unroll
        for (int c = 0; c < C_; ++c) sum += __expf(s_logit[c] - mx);
        const int lab = labels[b * T_ + t];
        const float p = __expf(s_logit[lab] - mx) / sum;

        const float denom = os + ts;
        const float dice = 1.f - (2.f * I + 1.f) / (denom + 1.f);

        out[(size_t)bq * T_ + t] = L - p + dice;
    }
}

extern "C" void kernel_launch(void* const* d_in, const int* in_sizes, int n_in,
                              void* d_out, int out_size, void* d_ws, size_t ws_size,
                              hipStream_t stream) {
    const float* out_probs     = (const float*)d_in[0]; // [B,Q,C]
    const float* out_masks     = (const float*)d_in[1]; // [B,Q,H,W]
    const float* target_masks  = (const float*)d_in[2]; // [B,T,H,W]
    const int*   target_labels = (const int*)d_in[3];   // [B,T]
    float* out = (float*)d_out;                         // [B,Q,T]

    float* partials = (float*)d_ws;                     // ~4.2 MB + 20 KB gsum

    partial_kernel<<<GROUPS_ * S_, 256, 0, stream>>>(out_masks, target_masks, partials);
    finalize_kernel<<<B_ * Q_, 64, 0, stream>>>(out_probs, target_labels, partials, out);
}